// Round 4
// baseline (705.644 us; speedup 1.0000x reference)
//
#include <hip/hip_runtime.h>
#include <stdint.h>

#define N_PIX 65536
#define KM 9

typedef __bf16  bf16x8 __attribute__((ext_vector_type(8)));
typedef float   f32x4  __attribute__((ext_vector_type(4)));
typedef unsigned short ushort;

__device__ __forceinline__ ushort f2bf(float f) {
    uint32_t u = __builtin_bit_cast(uint32_t, f);
    uint32_t r = (u + 0x7FFFu + ((u >> 16) & 1u)) >> 16;
    return (ushort)r;
}

// ---- workspace layout (bytes) ----
#define WS_BITS  0u              // uint32[65536]  256KB
#define WS_CNT   262144u
#define WS_CNT1  262208u
#define WS_SUMS  262272u         // float[9*256]
#define WS_MEANS 271488u         // float[9*256]
#define WS_W1T   282624u         // ushort 9*128*256
#define WS_W2T   872448u         // ushort 9*64*128
#define WS_W3T   1019904u        // ushort 9*32*64
#define WS_COV   1056768u        // float[9*1024]
#define WS_XPAD  2097152u        // bf16 [258][258][256] = 34.08 MB  [fsm->conv1]
#define WS_FV    2097152u        // float[65536*32] = 8.39 MB (overlaps XPAD; conv3->cov)
#define WS_PART  12582912u       // float[256*9216] = 9.44 MB (overlaps XPAD; cov->covred)
#define WS_C1PAD 36173824u       // bf16 [258][258][128] = 17.04 MB
#define WS_C2PAD 53212160u       // bf16 [258][258][64]  = 8.52 MB   (end ~61.7 MB)

// ---------------- zero the 1-px ring of a padded [258][258][C] bf16 buffer ----------------
template<int C>
__global__ void k_ring(ushort* p) {
    constexpr int CU = C / 2;                 // uint units per pixel
    int i = blockIdx.x * 256 + threadIdx.x;
    if (i >= 1028 * CU) return;
    int c = i % CU, px = i / CU;
    int row, col;
    if      (px < 258) { row = 0;   col = px; }
    else if (px < 516) { row = 257; col = px - 258; }
    else if (px < 772) { row = px - 516 + 1; col = 0; }
    else               { row = px - 772 + 1; col = 257; }
    ((uint32_t*)p)[(row * 258 + col) * CU + c] = 0u;
}

// ---------------- mask pack + counts ----------------
__global__ void k_pack(const int* __restrict__ masks, uint32_t* __restrict__ bits,
                       int* __restrict__ counts, int* __restrict__ cnt1) {
    int n = blockIdx.x * 256 + threadIdx.x;
    uint32_t fg = 0, f1 = 0;
#pragma unroll
    for (int k = 0; k < KM; ++k) {
        int m = masks[k * N_PIX + n];
        fg |= (uint32_t)(m > 0) << k;
        f1 |= (uint32_t)(m == 1) << k;
    }
    bits[n] = fg | (f1 << 16);
#pragma unroll
    for (int k = 0; k < KM; ++k) {
        unsigned long long b0 = __ballot((fg >> k) & 1);
        unsigned long long b1 = __ballot((f1 >> k) & 1);
        if ((threadIdx.x & 63) == 0) {
            atomicAdd(&counts[k], __popcll(b0));
            atomicAdd(&cnt1[k], __popcll(b1));
        }
    }
}

// ---------------- per-(mask,channel) sums ----------------
__global__ void k_sums(const float* __restrict__ x, const uint32_t* __restrict__ bits,
                       float* __restrict__ sums) {
    int c = blockIdx.x >> 4;
    int base = (blockIdx.x & 15) * 4096;
    float acc[KM];
#pragma unroll
    for (int k = 0; k < KM; ++k) acc[k] = 0.0f;
    const float* xc = x + (size_t)c * N_PIX;
    for (int i = 0; i < 16; ++i) {
        int px = base + i * 256 + threadIdx.x;
        float xv = xc[px];
        uint32_t b = bits[px];
#pragma unroll
        for (int k = 0; k < KM; ++k) acc[k] += ((b >> k) & 1) ? xv : 0.0f;
    }
#pragma unroll
    for (int k = 0; k < KM; ++k) {
        float v = acc[k];
        for (int off = 32; off; off >>= 1) v += __shfl_down(v, off);
        if ((threadIdx.x & 63) == 0) atomicAdd(&sums[k * 256 + c], v);
    }
}

__global__ void k_means(const float* __restrict__ sums, const int* __restrict__ counts,
                        float* __restrict__ means) {
    int k = blockIdx.x, c = threadIdx.x;
    means[k * 256 + c] = sums[k * 256 + c] / fmaxf((float)counts[k], 1.0f);
}

// ---------------- fsm (fp32 NCHW out) + bf16 padded-NHWC copy ----------------
__global__ void k_fsm(const float* __restrict__ x, const uint32_t* __restrict__ bits,
                      const int* __restrict__ counts, const float* __restrict__ means,
                      float* __restrict__ fsm, ushort* __restrict__ xpad) {
    __shared__ float mst[256 * 12];
    int tid = threadIdx.x;
    for (int t = tid; t < KM * 256; t += 256) {
        int k = t >> 8, c = t & 255;
        mst[c * 12 + k] = means[t];
    }
    __syncthreads();
    uint32_t vm = 0;
#pragma unroll
    for (int k = 0; k < KM; ++k) vm |= (uint32_t)(counts[k] >= 10) << k;
    int px = blockIdx.x * 256 + tid;
    int c0 = blockIdx.y * 128;
    uint32_t sel = bits[px] & vm & 0x1FFu;
    int kl = 0; float have = 0.0f;
    if (sel) { kl = 31 - __clz((int)sel); have = 1.0f; }
    int y = px >> 8, xx = px & 255;
    size_t pbase = ((size_t)(y + 1) * 258 + (xx + 1)) * 256;
    for (int cb = 0; cb < 128; cb += 8) {
        int c = c0 + cb;
        uint32_t pk[4];
#pragma unroll
        for (int j = 0; j < 8; j += 2) {
            float v0 = x[(size_t)(c + j) * N_PIX + px]     - have * mst[(c + j) * 12 + kl];
            float v1 = x[(size_t)(c + j + 1) * N_PIX + px] - have * mst[(c + j + 1) * 12 + kl];
            fsm[(size_t)(c + j) * N_PIX + px] = v0;
            fsm[(size_t)(c + j + 1) * N_PIX + px] = v1;
            pk[j >> 1] = (uint32_t)f2bf(v0) | ((uint32_t)f2bf(v1) << 16);
        }
        uint4 w; w.x = pk[0]; w.y = pk[1]; w.z = pk[2]; w.w = pk[3];
        *(uint4*)&xpad[pbase + c] = w;
    }
}

// ---------------- weight pack: OIHW fp32 -> [tap][oc][ic] bf16 ----------------
__global__ void k_wpack(const float* __restrict__ w, ushort* __restrict__ wt,
                        int total, int OC, int IC) {
    int idx = blockIdx.x * 256 + threadIdx.x;
    if (idx >= total) return;
    int oc = idx / IC, ic = idx - oc * IC;
    const float* src = w + (size_t)idx * 9;
#pragma unroll
    for (int t = 0; t < 9; ++t)
        wt[((size_t)t * OC + oc) * IC + ic] = f2bf(src[t]);
}

// ---------------- MFMA implicit-GEMM 3x3 conv, padded NHWC bf16 ----------------
// 4 waves; wave tile 32px x (16*NT)oc; block = (32*PXG)px x (16*NT*(4/PXG))oc
// weights in registers per icc; T14 async reg-staging; single LDS buffer.
template<int IC, int OC, int NT, int PXG, bool RELU, bool F32OUT>
__global__ __launch_bounds__(256) void k_convm(const ushort* __restrict__ xin,
                                               const ushort* __restrict__ wt,
                                               const float* __restrict__ bias,
                                               ushort* __restrict__ ypad,
                                               float* __restrict__ yf) {
    constexpr int NC   = IC / 32;
    constexpr int BPX  = 32 * PXG;
    constexpr int SEG  = 256 / BPX;
    constexpr int PXP  = BPX + 2;
    constexpr int RW   = PXP * 4;            // 16B units per halo row
    constexpr int UNITS = 3 * RW;
    constexpr int NCH  = (UNITS + 63) / 64;  // 64-lane chunks
    constexpr int NV   = (NCH + 3) / 4;      // chunks per wave
    static_assert(OC == 16 * NT * (4 / PXG), "tile mismatch");

    __shared__ ushort xs[NCH * 512];         // [chunk][lane][8ch]

    const int tid = threadIdx.x, lane = tid & 63, wv = tid >> 6;
    const int lo = lane & 15, kg = lane >> 4;
    const int y0 = blockIdx.x / SEG;
    const int x0 = (blockIdx.x % SEG) * BPX;
    const int wvpx = (wv % PXG) * 32;
    const int oc0  = (wv / PXG) * 16 * NT;

    // per-lane stage source offsets (icc-independent part), in ushort units
    uint32_t voff[NV];
#pragma unroll
    for (int j = 0; j < NV; ++j) {
        int ch = wv + j * 4;
        int u = ch * 64 + lane;
        u = (u < UNITS) ? u : (UNITS - 1);
        int row = u / RW;
        int rem = u - row * RW;
        int px = rem >> 2, icg = rem & 3;
        voff[j] = (uint32_t)(((y0 + row) * 258 + (x0 + px)) * IC + icg * 8);
    }

    const ushort* wlane = wt + (size_t)(oc0 + lo) * IC + kg * 8;
    const int abase = (wvpx + lo) * 32 + kg * 8;   // ushort index in xs

    f32x4 acc[2][NT];
#pragma unroll
    for (int m = 0; m < 2; ++m)
#pragma unroll
        for (int n = 0; n < NT; ++n) acc[m][n] = (f32x4){0.f, 0.f, 0.f, 0.f};
    float bs[NT];
#pragma unroll
    for (int n = 0; n < NT; ++n) bs[n] = bias[oc0 + n * 16 + lo];

    uint4 sreg[NV];
#pragma unroll
    for (int j = 0; j < NV; ++j)
        if (wv + j * 4 < NCH) sreg[j] = *(const uint4*)(xin + voff[j]);

    for (int icc = 0; icc < NC; ++icc) {
        // write staged regs -> LDS
#pragma unroll
        for (int j = 0; j < NV; ++j) {
            int ch = wv + j * 4;
            if (ch < NCH) *(uint4*)(xs + ch * 512 + lane * 8) = sreg[j];
        }
        __syncthreads();
        // weights for this icc -> regs
        bf16x8 wf[9][NT];
#pragma unroll
        for (int tap = 0; tap < 9; ++tap)
#pragma unroll
            for (int n = 0; n < NT; ++n)
                wf[tap][n] = __builtin_bit_cast(bf16x8,
                    *(const uint4*)(wlane + ((size_t)tap * OC + n * 16) * IC + icc * 32));
        // prefetch next icc's x-tile into regs (flies during compute)
        if (icc + 1 < NC) {
#pragma unroll
            for (int j = 0; j < NV; ++j)
                if (wv + j * 4 < NCH)
                    sreg[j] = *(const uint4*)(xin + voff[j] + (icc + 1) * 32);
        }
#pragma unroll
        for (int tr = 0; tr < 3; ++tr)
#pragma unroll
            for (int tc = 0; tc < 3; ++tc) {
                bf16x8 a0 = __builtin_bit_cast(bf16x8,
                    *(const uint4*)(xs + abase + (tr * PXP + tc) * 32));
                bf16x8 a1 = __builtin_bit_cast(bf16x8,
                    *(const uint4*)(xs + abase + (tr * PXP + tc) * 32 + 512));
#pragma unroll
                for (int n = 0; n < NT; ++n) {
                    acc[0][n] = __builtin_amdgcn_mfma_f32_16x16x32_bf16(a0, wf[tr * 3 + tc][n], acc[0][n], 0, 0, 0);
                    acc[1][n] = __builtin_amdgcn_mfma_f32_16x16x32_bf16(a1, wf[tr * 3 + tc][n], acc[1][n], 0, 0, 0);
                }
            }
        __syncthreads();
    }
#pragma unroll
    for (int m = 0; m < 2; ++m) {
        int pxl = x0 + wvpx + m * 16 + kg * 4;
#pragma unroll
        for (int n = 0; n < NT; ++n) {
            int oc = oc0 + n * 16 + lo;
#pragma unroll
            for (int r = 0; r < 4; ++r) {
                float v = acc[m][n][r] + bs[n];
                if (RELU) v = fmaxf(v, 0.0f);
                if (F32OUT) yf[((size_t)y0 * 256 + pxl + r) * OC + oc] = v;
                else        ypad[((size_t)(y0 + 1) * 258 + (pxl + r) + 1) * OC + oc] = f2bf(v);
            }
        }
    }
}

// ---------------- masked covariance partials (fv = NHWC fp32 [px][32]) ----------------
__global__ __launch_bounds__(256) void k_cov(const float* __restrict__ fv,
                                             const uint32_t* __restrict__ bits,
                                             float* __restrict__ part) {
    __shared__ float sf[32 * 257];
    __shared__ uint32_t sb[256];
    int px0 = blockIdx.x * 256;
    int tid = threadIdx.x;
    const float4* src = (const float4*)(fv + (size_t)(px0 + tid) * 32);
#pragma unroll
    for (int q = 0; q < 8; ++q) {
        float4 v = src[q];
        sf[(q * 4 + 0) * 257 + tid] = v.x;
        sf[(q * 4 + 1) * 257 + tid] = v.y;
        sf[(q * 4 + 2) * 257 + tid] = v.z;
        sf[(q * 4 + 3) * 257 + tid] = v.w;
    }
    sb[tid] = bits[px0 + tid] >> 16;
    __syncthreads();
    int c = tid >> 3;
    int d4 = (tid & 7) * 4;
    float a[KM][4];
#pragma unroll
    for (int k = 0; k < KM; ++k)
#pragma unroll
        for (int j = 0; j < 4; ++j) a[k][j] = 0.0f;
#pragma unroll 2
    for (int px = 0; px < 256; ++px) {
        float fc = sf[c * 257 + px];
        float f0 = sf[(d4 + 0) * 257 + px];
        float f1 = sf[(d4 + 1) * 257 + px];
        float f2 = sf[(d4 + 2) * 257 + px];
        float f3 = sf[(d4 + 3) * 257 + px];
        uint32_t b = sb[px];
#pragma unroll
        for (int k = 0; k < KM; ++k) {
            float fm = ((b >> k) & 1) ? fc : 0.0f;
            a[k][0] = fmaf(fm, f0, a[k][0]);
            a[k][1] = fmaf(fm, f1, a[k][1]);
            a[k][2] = fmaf(fm, f2, a[k][2]);
            a[k][3] = fmaf(fm, f3, a[k][3]);
        }
    }
    float* po = part + (size_t)blockIdx.x * 9216 + (c * 32 + d4);
#pragma unroll
    for (int k = 0; k < KM; ++k)
#pragma unroll
        for (int j = 0; j < 4; ++j) po[k * 1024 + j] = a[k][j];
}

__global__ void k_covred(const float* __restrict__ part, float* __restrict__ cov) {
    int p = blockIdx.x * 256 + threadIdx.x;
    float s = 0.0f;
    for (int b = 0; b < 256; ++b) s += part[(size_t)b * 9216 + p];
    cov[p] = s;
}

// ---------------- FC + validity ----------------
__global__ void k_fc(const float* __restrict__ cov, const int* __restrict__ cnt1,
                     const float* __restrict__ fcw, const float* __restrict__ fcb,
                     float* __restrict__ trans) {
    int k = blockIdx.x;
    int j = blockIdx.y * 256 + threadIdx.x;
    __shared__ float sc[1024];
    int c1 = cnt1[k];
    float inv = 1.0f / fmaxf((float)c1, 1.0f);
    for (int t = threadIdx.x; t < 1024; t += 256) sc[t] = cov[k * 1024 + t] * inv;
    __syncthreads();
    const float4* wrow = (const float4*)(fcw + (size_t)j * 1024);
    float acc = fcb[j];
#pragma unroll 4
    for (int i4 = 0; i4 < 256; ++i4) {
        float4 wv = wrow[i4];
        acc += sc[i4 * 4 + 0] * wv.x + sc[i4 * 4 + 1] * wv.y +
               sc[i4 * 4 + 2] * wv.z + sc[i4 * 4 + 3] * wv.w;
    }
    trans[k * 1024 + j] = (c1 >= 10) ? acc : 0.0f;
}

extern "C" void kernel_launch(void* const* d_in, const int* in_sizes, int n_in,
                              void* d_out, int out_size, void* d_ws, size_t ws_size,
                              hipStream_t stream) {
    const float* x     = (const float*)d_in[0];
    const int*   masks = (const int*)  d_in[1];
    const float* w1    = (const float*)d_in[2];
    const float* b1    = (const float*)d_in[3];
    const float* w2    = (const float*)d_in[4];
    const float* b2    = (const float*)d_in[5];
    const float* w3    = (const float*)d_in[6];
    const float* b3    = (const float*)d_in[7];
    const float* fcw   = (const float*)d_in[8];
    const float* fcb   = (const float*)d_in[9];

    float* out   = (float*)d_out;
    float* trans = out;
    float* fsm   = out + KM * 1024;

    char* ws = (char*)d_ws;
    uint32_t* bits = (uint32_t*)(ws + WS_BITS);
    int*   counts  = (int*)  (ws + WS_CNT);
    int*   cnt1    = (int*)  (ws + WS_CNT1);
    float* sums    = (float*)(ws + WS_SUMS);
    float* means   = (float*)(ws + WS_MEANS);
    ushort* w1t = (ushort*)(ws + WS_W1T);
    ushort* w2t = (ushort*)(ws + WS_W2T);
    ushort* w3t = (ushort*)(ws + WS_W3T);
    float* cov     = (float*)(ws + WS_COV);
    ushort* xpad  = (ushort*)(ws + WS_XPAD);
    ushort* c1pad = (ushort*)(ws + WS_C1PAD);
    ushort* c2pad = (ushort*)(ws + WS_C2PAD);
    float* fv      = (float*)(ws + WS_FV);
    float* part    = (float*)(ws + WS_PART);

    hipMemsetAsync(ws + WS_CNT, 0, 64 + 64 + 9216, stream);

    k_ring<256><<<(1028 * 128 + 255) / 256, 256, 0, stream>>>(xpad);
    k_ring<128><<<(1028 *  64 + 255) / 256, 256, 0, stream>>>(c1pad);
    k_ring< 64><<<(1028 *  32 + 255) / 256, 256, 0, stream>>>(c2pad);

    k_wpack<<<128, 256, 0, stream>>>(w1, w1t, 128 * 256, 128, 256);
    k_wpack<<< 32, 256, 0, stream>>>(w2, w2t,  64 * 128,  64, 128);
    k_wpack<<<  8, 256, 0, stream>>>(w3, w3t,  32 *  64,  32,  64);

    k_pack <<<256, 256, 0, stream>>>(masks, bits, counts, cnt1);
    k_sums <<<4096, 256, 0, stream>>>(x, bits, sums);
    k_means<<<KM, 256, 0, stream>>>(sums, counts, means);
    k_fsm  <<<dim3(256, 2), 256, 0, stream>>>(x, bits, counts, means, fsm, xpad);

    k_convm<256, 128, 4, 2, true,  false><<<1024, 256, 0, stream>>>(xpad,  w1t, b1, c1pad, nullptr);
    k_convm<128,  64, 4, 4, true,  false><<< 512, 256, 0, stream>>>(c1pad, w2t, b2, c2pad, nullptr);
    k_convm< 64,  32, 2, 4, false, true ><<< 512, 256, 0, stream>>>(c2pad, w3t, b3, nullptr, fv);

    k_cov   <<<256, 256, 0, stream>>>(fv, bits, part);
    k_covred<<<36, 256, 0, stream>>>(part, cov);
    k_fc    <<<dim3(KM, 4), 256, 0, stream>>>(cov, cnt1, fcw, fcb, trans);
}

// Round 5
// 680.935 us; speedup vs baseline: 1.0363x; 1.0363x over previous
//
#include <hip/hip_runtime.h>
#include <stdint.h>

#define N_PIX 65536
#define KM 9

typedef __bf16  bf16x8 __attribute__((ext_vector_type(8)));
typedef float   f32x4  __attribute__((ext_vector_type(4)));
typedef unsigned short ushort;

__device__ __forceinline__ ushort f2bf(float f) {
    uint32_t u = __builtin_bit_cast(uint32_t, f);
    uint32_t r = (u + 0x7FFFu + ((u >> 16) & 1u)) >> 16;
    return (ushort)r;
}

// ---- workspace layout (bytes) ----
#define WS_BITS  0u              // uint32[65536]  256KB
#define WS_CNT   262144u
#define WS_CNT1  262208u
#define WS_SUMS  262272u         // float[9*256]
#define WS_MEANS 271488u         // float[9*256]
#define WS_W1T   282624u         // ushort 9*128*256
#define WS_W2T   872448u         // ushort 9*64*128
#define WS_W3T   1019904u        // ushort 9*32*64
#define WS_COV   1056768u        // float[9*1024]
#define WS_XPAD  2097152u        // bf16 [258][258][256] = 34.08 MB  [fsm->conv1]
#define WS_FV    2097152u        // float[65536*32] = 8.39 MB (overlaps XPAD; conv3->cov)
#define WS_PART  12582912u       // float[256*9216] = 9.44 MB (overlaps XPAD; cov->covred)
#define WS_C1PAD 36173824u       // bf16 [258][258][128] = 17.04 MB
#define WS_C2PAD 53212160u       // bf16 [258][258][64]  = 8.52 MB

// ---------------- zero the 1-px ring of a padded [258][258][C] bf16 buffer ----------------
template<int C>
__global__ void k_ring(ushort* p) {
    constexpr int CU = C / 2;
    int i = blockIdx.x * 256 + threadIdx.x;
    if (i >= 1028 * CU) return;
    int c = i % CU, px = i / CU;
    int row, col;
    if      (px < 258) { row = 0;   col = px; }
    else if (px < 516) { row = 257; col = px - 258; }
    else if (px < 772) { row = px - 516 + 1; col = 0; }
    else               { row = px - 772 + 1; col = 257; }
    ((uint32_t*)p)[(row * 258 + col) * CU + c] = 0u;
}

// ---------------- mask pack + counts ----------------
__global__ void k_pack(const int* __restrict__ masks, uint32_t* __restrict__ bits,
                       int* __restrict__ counts, int* __restrict__ cnt1) {
    int n = blockIdx.x * 256 + threadIdx.x;
    uint32_t fg = 0, f1 = 0;
#pragma unroll
    for (int k = 0; k < KM; ++k) {
        int m = masks[k * N_PIX + n];
        fg |= (uint32_t)(m > 0) << k;
        f1 |= (uint32_t)(m == 1) << k;
    }
    bits[n] = fg | (f1 << 16);
#pragma unroll
    for (int k = 0; k < KM; ++k) {
        unsigned long long b0 = __ballot((fg >> k) & 1);
        unsigned long long b1 = __ballot((f1 >> k) & 1);
        if ((threadIdx.x & 63) == 0) {
            atomicAdd(&counts[k], __popcll(b0));
            atomicAdd(&cnt1[k], __popcll(b1));
        }
    }
}

// ---------------- per-(mask,channel) sums ----------------
__global__ void k_sums(const float* __restrict__ x, const uint32_t* __restrict__ bits,
                       float* __restrict__ sums) {
    int c = blockIdx.x >> 4;
    int base = (blockIdx.x & 15) * 4096;
    float acc[KM];
#pragma unroll
    for (int k = 0; k < KM; ++k) acc[k] = 0.0f;
    const float* xc = x + (size_t)c * N_PIX;
    for (int i = 0; i < 16; ++i) {
        int px = base + i * 256 + threadIdx.x;
        float xv = xc[px];
        uint32_t b = bits[px];
#pragma unroll
        for (int k = 0; k < KM; ++k) acc[k] += ((b >> k) & 1) ? xv : 0.0f;
    }
#pragma unroll
    for (int k = 0; k < KM; ++k) {
        float v = acc[k];
        for (int off = 32; off; off >>= 1) v += __shfl_down(v, off);
        if ((threadIdx.x & 63) == 0) atomicAdd(&sums[k * 256 + c], v);
    }
}

__global__ void k_means(const float* __restrict__ sums, const int* __restrict__ counts,
                        float* __restrict__ means) {
    int k = blockIdx.x, c = threadIdx.x;
    means[k * 256 + c] = sums[k * 256 + c] / fmaxf((float)counts[k], 1.0f);
}

// ---------------- fsm (fp32 NCHW out) + bf16 padded-NHWC copy ----------------
__global__ void k_fsm(const float* __restrict__ x, const uint32_t* __restrict__ bits,
                      const int* __restrict__ counts, const float* __restrict__ means,
                      float* __restrict__ fsm, ushort* __restrict__ xpad) {
    __shared__ float mst[256 * 12];
    int tid = threadIdx.x;
    for (int t = tid; t < KM * 256; t += 256) {
        int k = t >> 8, c = t & 255;
        mst[c * 12 + k] = means[t];
    }
    __syncthreads();
    uint32_t vm = 0;
#pragma unroll
    for (int k = 0; k < KM; ++k) vm |= (uint32_t)(counts[k] >= 10) << k;
    int px = blockIdx.x * 256 + tid;
    int c0 = blockIdx.y * 128;
    uint32_t sel = bits[px] & vm & 0x1FFu;
    int kl = 0; float have = 0.0f;
    if (sel) { kl = 31 - __clz((int)sel); have = 1.0f; }
    int y = px >> 8, xx = px & 255;
    size_t pbase = ((size_t)(y + 1) * 258 + (xx + 1)) * 256;
    for (int cb = 0; cb < 128; cb += 8) {
        int c = c0 + cb;
        uint32_t pk[4];
#pragma unroll
        for (int j = 0; j < 8; j += 2) {
            float v0 = x[(size_t)(c + j) * N_PIX + px]     - have * mst[(c + j) * 12 + kl];
            float v1 = x[(size_t)(c + j + 1) * N_PIX + px] - have * mst[(c + j + 1) * 12 + kl];
            fsm[(size_t)(c + j) * N_PIX + px] = v0;
            fsm[(size_t)(c + j + 1) * N_PIX + px] = v1;
            pk[j >> 1] = (uint32_t)f2bf(v0) | ((uint32_t)f2bf(v1) << 16);
        }
        uint4 w; w.x = pk[0]; w.y = pk[1]; w.z = pk[2]; w.w = pk[3];
        *(uint4*)&xpad[pbase + c] = w;
    }
}

// ---------------- weight pack: OIHW fp32 -> [tap][oc][ic] bf16 ----------------
__global__ void k_wpack(const float* __restrict__ w, ushort* __restrict__ wt,
                        int total, int OC, int IC) {
    int idx = blockIdx.x * 256 + threadIdx.x;
    if (idx >= total) return;
    int oc = idx / IC, ic = idx - oc * IC;
    const float* src = w + (size_t)idx * 9;
#pragma unroll
    for (int t = 0; t < 9; ++t)
        wt[((size_t)t * OC + oc) * IC + ic] = f2bf(src[t]);
}

// ---------------- MFMA implicit-GEMM 3x3 conv, padded NHWC bf16 ----------------
// Block: 64 px x OC, 4 waves = 2 px-groups x 2 oc-groups; wave = 32 px x (16*NT) oc.
// Weights: 2-tap-deep register pipeline (8*NT regs). X: T14 reg prefetch -> LDS.
template<int IC, int OC, int NT, bool RELU, bool F32OUT>
__global__ __launch_bounds__(256, 4) void k_convm(const ushort* __restrict__ xin,
                                                  const ushort* __restrict__ wt,
                                                  const float* __restrict__ bias,
                                                  ushort* __restrict__ ypad,
                                                  float* __restrict__ yf) {
    constexpr int NC  = IC / 32;
    constexpr int PXP = 66;                 // 64 + 2 halo
    constexpr int RW  = PXP * 4;            // 16B units per halo row
    constexpr int UNITS = 3 * RW;           // 792
    constexpr int NCH = (UNITS + 63) / 64;  // 13
    constexpr int NV  = (NCH + 3) / 4;      // 4
    static_assert(OC == NT * 32, "2 oc-groups of 16*NT");

    __shared__ ushort xs[NCH * 512];        // 13.3 KB

    const int tid = threadIdx.x, lane = tid & 63, wv = tid >> 6;
    const int lo = lane & 15, kg = lane >> 4;
    const int y0 = blockIdx.x >> 2;
    const int x0 = (blockIdx.x & 3) << 6;
    const int wvpx = (wv & 1) << 5;         // px group 0/32
    const int oc0  = (wv >> 1) * NT * 16;   // oc group

    uint32_t voff[NV];
#pragma unroll
    for (int j = 0; j < NV; ++j) {
        int ch = wv + j * 4;
        int u = ch * 64 + lane;
        u = (u < UNITS) ? u : (UNITS - 1);
        int row = u / RW;
        int rem = u - row * RW;
        int px = rem >> 2, icg = rem & 3;
        voff[j] = (uint32_t)(((y0 + row) * 258 + (x0 + px)) * IC + icg * 8);
    }

    const ushort* wlane = wt + (size_t)(oc0 + lo) * IC + kg * 8;
    const int abase = (wvpx + lo) * 32 + kg * 8;

    f32x4 acc[2][NT];
#pragma unroll
    for (int m = 0; m < 2; ++m)
#pragma unroll
        for (int n = 0; n < NT; ++n) acc[m][n] = (f32x4){0.f, 0.f, 0.f, 0.f};
    float bs[NT];
#pragma unroll
    for (int n = 0; n < NT; ++n) bs[n] = bias[oc0 + n * 16 + lo];

    uint4 sreg[NV];
#pragma unroll
    for (int j = 0; j < NV; ++j)
        if (wv + j * 4 < NCH) sreg[j] = *(const uint4*)(xin + voff[j]);

    for (int icc = 0; icc < NC; ++icc) {
#pragma unroll
        for (int j = 0; j < NV; ++j) {
            int ch = wv + j * 4;
            if (ch < NCH) *(uint4*)(xs + ch * 512 + lane * 8) = sreg[j];
        }
        __syncthreads();
        if (icc + 1 < NC) {
#pragma unroll
            for (int j = 0; j < NV; ++j)
                if (wv + j * 4 < NCH)
                    sreg[j] = *(const uint4*)(xin + voff[j] + (icc + 1) * 32);
        }
        const ushort* wicc = wlane + icc * 32;
        // 2-tap-deep weight register pipeline
        uint4 wb0[NT], wb1[NT];
#pragma unroll
        for (int n = 0; n < NT; ++n) {
            wb0[n] = *(const uint4*)(wicc + ((size_t)0 * OC + n * 16) * IC);
            wb1[n] = *(const uint4*)(wicc + ((size_t)1 * OC + n * 16) * IC);
        }
#pragma unroll
        for (int tap = 0; tap < 9; ++tap) {
            const int tr = tap / 3, tc = tap % 3;
            bf16x8 a0 = __builtin_bit_cast(bf16x8,
                *(const uint4*)(xs + abase + (tr * PXP + tc) * 32));
            bf16x8 a1 = __builtin_bit_cast(bf16x8,
                *(const uint4*)(xs + abase + (tr * PXP + tc) * 32 + 512));
#pragma unroll
            for (int n = 0; n < NT; ++n) {
                bf16x8 wfr = __builtin_bit_cast(bf16x8, (tap & 1) ? wb1[n] : wb0[n]);
                acc[0][n] = __builtin_amdgcn_mfma_f32_16x16x32_bf16(a0, wfr, acc[0][n], 0, 0, 0);
                acc[1][n] = __builtin_amdgcn_mfma_f32_16x16x32_bf16(a1, wfr, acc[1][n], 0, 0, 0);
            }
            if (tap + 2 < 9) {
#pragma unroll
                for (int n = 0; n < NT; ++n) {
                    uint4 v = *(const uint4*)(wicc + ((size_t)(tap + 2) * OC + n * 16) * IC);
                    if (tap & 1) wb1[n] = v; else wb0[n] = v;
                }
            }
        }
        __syncthreads();
    }
#pragma unroll
    for (int m = 0; m < 2; ++m) {
        int pxl = x0 + wvpx + m * 16 + kg * 4;
#pragma unroll
        for (int n = 0; n < NT; ++n) {
            int oc = oc0 + n * 16 + lo;
#pragma unroll
            for (int r = 0; r < 4; ++r) {
                float v = acc[m][n][r] + bs[n];
                if (RELU) v = fmaxf(v, 0.0f);
                if (F32OUT) yf[((size_t)y0 * 256 + pxl + r) * OC + oc] = v;
                else        ypad[((size_t)(y0 + 1) * 258 + (pxl + r) + 1) * OC + oc] = f2bf(v);
            }
        }
    }
}

// ---------------- masked covariance partials (fv = NHWC fp32 [px][32]) ----------------
__global__ __launch_bounds__(256) void k_cov(const float* __restrict__ fv,
                                             const uint32_t* __restrict__ bits,
                                             float* __restrict__ part) {
    __shared__ float sf[32 * 257];
    __shared__ uint32_t sb[256];
    int px0 = blockIdx.x * 256;
    int tid = threadIdx.x;
    const float4* src = (const float4*)(fv + (size_t)(px0 + tid) * 32);
#pragma unroll
    for (int q = 0; q < 8; ++q) {
        float4 v = src[q];
        sf[(q * 4 + 0) * 257 + tid] = v.x;
        sf[(q * 4 + 1) * 257 + tid] = v.y;
        sf[(q * 4 + 2) * 257 + tid] = v.z;
        sf[(q * 4 + 3) * 257 + tid] = v.w;
    }
    sb[tid] = bits[px0 + tid] >> 16;
    __syncthreads();
    int c = tid >> 3;
    int d4 = (tid & 7) * 4;
    float a[KM][4];
#pragma unroll
    for (int k = 0; k < KM; ++k)
#pragma unroll
        for (int j = 0; j < 4; ++j) a[k][j] = 0.0f;
#pragma unroll 2
    for (int px = 0; px < 256; ++px) {
        float fc = sf[c * 257 + px];
        float f0 = sf[(d4 + 0) * 257 + px];
        float f1 = sf[(d4 + 1) * 257 + px];
        float f2 = sf[(d4 + 2) * 257 + px];
        float f3 = sf[(d4 + 3) * 257 + px];
        uint32_t b = sb[px];
#pragma unroll
        for (int k = 0; k < KM; ++k) {
            float fm = ((b >> k) & 1) ? fc : 0.0f;
            a[k][0] = fmaf(fm, f0, a[k][0]);
            a[k][1] = fmaf(fm, f1, a[k][1]);
            a[k][2] = fmaf(fm, f2, a[k][2]);
            a[k][3] = fmaf(fm, f3, a[k][3]);
        }
    }
    float* po = part + (size_t)blockIdx.x * 9216 + (c * 32 + d4);
#pragma unroll
    for (int k = 0; k < KM; ++k)
#pragma unroll
        for (int j = 0; j < 4; ++j) po[k * 1024 + j] = a[k][j];
}

__global__ void k_covred(const float* __restrict__ part, float* __restrict__ cov) {
    int p = blockIdx.x * 256 + threadIdx.x;
    float s = 0.0f;
    for (int b = 0; b < 256; ++b) s += part[(size_t)b * 9216 + p];
    cov[p] = s;
}

// ---------------- FC + validity ----------------
__global__ void k_fc(const float* __restrict__ cov, const int* __restrict__ cnt1,
                     const float* __restrict__ fcw, const float* __restrict__ fcb,
                     float* __restrict__ trans) {
    int k = blockIdx.x;
    int j = blockIdx.y * 256 + threadIdx.x;
    __shared__ float sc[1024];
    int c1 = cnt1[k];
    float inv = 1.0f / fmaxf((float)c1, 1.0f);
    for (int t = threadIdx.x; t < 1024; t += 256) sc[t] = cov[k * 1024 + t] * inv;
    __syncthreads();
    const float4* wrow = (const float4*)(fcw + (size_t)j * 1024);
    float acc = fcb[j];
#pragma unroll 4
    for (int i4 = 0; i4 < 256; ++i4) {
        float4 wv = wrow[i4];
        acc += sc[i4 * 4 + 0] * wv.x + sc[i4 * 4 + 1] * wv.y +
               sc[i4 * 4 + 2] * wv.z + sc[i4 * 4 + 3] * wv.w;
    }
    trans[k * 1024 + j] = (c1 >= 10) ? acc : 0.0f;
}

extern "C" void kernel_launch(void* const* d_in, const int* in_sizes, int n_in,
                              void* d_out, int out_size, void* d_ws, size_t ws_size,
                              hipStream_t stream) {
    const float* x     = (const float*)d_in[0];
    const int*   masks = (const int*)  d_in[1];
    const float* w1    = (const float*)d_in[2];
    const float* b1    = (const float*)d_in[3];
    const float* w2    = (const float*)d_in[4];
    const float* b2    = (const float*)d_in[5];
    const float* w3    = (const float*)d_in[6];
    const float* b3    = (const float*)d_in[7];
    const float* fcw   = (const float*)d_in[8];
    const float* fcb   = (const float*)d_in[9];

    float* out   = (float*)d_out;
    float* trans = out;
    float* fsm   = out + KM * 1024;

    char* ws = (char*)d_ws;
    uint32_t* bits = (uint32_t*)(ws + WS_BITS);
    int*   counts  = (int*)  (ws + WS_CNT);
    int*   cnt1    = (int*)  (ws + WS_CNT1);
    float* sums    = (float*)(ws + WS_SUMS);
    float* means   = (float*)(ws + WS_MEANS);
    ushort* w1t = (ushort*)(ws + WS_W1T);
    ushort* w2t = (ushort*)(ws + WS_W2T);
    ushort* w3t = (ushort*)(ws + WS_W3T);
    float* cov     = (float*)(ws + WS_COV);
    ushort* xpad  = (ushort*)(ws + WS_XPAD);
    ushort* c1pad = (ushort*)(ws + WS_C1PAD);
    ushort* c2pad = (ushort*)(ws + WS_C2PAD);
    float* fv      = (float*)(ws + WS_FV);
    float* part    = (float*)(ws + WS_PART);

    hipMemsetAsync(ws + WS_CNT, 0, 64 + 64 + 9216, stream);

    k_ring<256><<<(1028 * 128 + 255) / 256, 256, 0, stream>>>(xpad);
    k_ring<128><<<(1028 *  64 + 255) / 256, 256, 0, stream>>>(c1pad);
    k_ring< 64><<<(1028 *  32 + 255) / 256, 256, 0, stream>>>(c2pad);

    k_wpack<<<128, 256, 0, stream>>>(w1, w1t, 128 * 256, 128, 256);
    k_wpack<<< 32, 256, 0, stream>>>(w2, w2t,  64 * 128,  64, 128);
    k_wpack<<<  8, 256, 0, stream>>>(w3, w3t,  32 *  64,  32,  64);

    k_pack <<<256, 256, 0, stream>>>(masks, bits, counts, cnt1);
    k_sums <<<4096, 256, 0, stream>>>(x, bits, sums);
    k_means<<<KM, 256, 0, stream>>>(sums, counts, means);
    k_fsm  <<<dim3(256, 2), 256, 0, stream>>>(x, bits, counts, means, fsm, xpad);

    k_convm<256, 128, 4, true,  false><<<1024, 256, 0, stream>>>(xpad,  w1t, b1, c1pad, nullptr);
    k_convm<128,  64, 2, true,  false><<<1024, 256, 0, stream>>>(c1pad, w2t, b2, c2pad, nullptr);
    k_convm< 64,  32, 1, false, true ><<<1024, 256, 0, stream>>>(c2pad, w3t, b3, nullptr, fv);

    k_cov   <<<256, 256, 0, stream>>>(fv, bits, part);
    k_covred<<<36, 256, 0, stream>>>(part, cov);
    k_fc    <<<dim3(KM, 4), 256, 0, stream>>>(cov, cnt1, fcw, fcb, trans);
}